// Round 11
// baseline (403.893 us; speedup 1.0000x reference)
//
#include <hip/hip_runtime.h>

// QKVAttention: qkv [8, 3072, 1024] fp32 -> out [8, 1024, 1024] fp32
// Prepass: K (transpose+swizzle) and V (convert+swizzle) fp16 to ws.
// Attn: 1024-thread blocks, 16 waves = 8 t-groups x 2 s-halves. Each wave:
// 32 t-rows (2 subs), HALF the s-strips per tile -> per-CU LDS traffic
// unchanged vs r6 but 8 waves/SIMD (vs 4) hide the QK->exp->PV latency.
// K+V LDS dbuf via global_load_lds, 1 barrier/iter. PV uses mfma_16x16x16
// (QK C-fragment feeds PV A-operand in registers). Epilogue merges the two
// s-halves via LDS (2 phases of 4 t-groups, padded [64][33]).
// r9 lesson: V must stay LDS-staged (direct L2 reads are 64-line/instr
// uncoalesced, 146us). r4 lesson: keep per-wave register set at 64 VGPR.

typedef __attribute__((ext_vector_type(8))) _Float16 f16x8;
typedef __attribute__((ext_vector_type(4))) _Float16 f16x4;
typedef __attribute__((ext_vector_type(4))) float f32x4;

#define MAT_HALVES 8388608   // 16 MB per matrix (128 heads * 64 * 1024 halves)
#define WS_BYTES   33554432  // K + V fp16

#define ASYNC16(g, l) __builtin_amdgcn_global_load_lds(                    \
    (__attribute__((address_space(1))) void*)(void*)(g),                   \
    (__attribute__((address_space(3))) void*)(void*)(l), 16, 0, 0)

// ---------------- Pre-pass: K transpose + V convert, fp32 -> fp16 ------------
// Kt [head][s][64c], chunk c' = cb ^ (s&7)
// Vh [head][c][1024s], within each 64-s tile chunk s' = sb ^ (c&7)
__global__ __launch_bounds__(256) void prepass_kv(
    const float* __restrict__ qkv, _Float16* __restrict__ ws) {
    __shared__ float ft[64][68];
    const int tid = threadIdx.x;
    const int bid = blockIdx.x;       // 4096 = 2 mats * 128 heads * 16 blocks
    const int mat = bid >> 11;        // 0 K, 1 V
    const int idx = bid & 2047;
    const int head = idx >> 4;
    const int blk  = idx & 15;
    const int b = head >> 4, h = head & 15;
    const float* src = qkv + (size_t)b * 3072 * 1024
                           + (size_t)((1 + mat) * 1024 + h * 64) * 1024;
    const int s0 = blk * 64;
    if (mat == 0) {
#pragma unroll
        for (int i = 0; i < 4; ++i) {
            const int c = i * 16 + (tid >> 4);
            const int s = (tid & 15) * 4;
            const float4 v = *(const float4*)(src + (size_t)c * 1024 + s0 + s);
            ft[s + 0][c] = v.x;
            ft[s + 1][c] = v.y;
            ft[s + 2][c] = v.z;
            ft[s + 3][c] = v.w;
        }
        __syncthreads();
        _Float16* dst = ws + (size_t)head * 65536 + (size_t)s0 * 64;
#pragma unroll
        for (int r = 0; r < 2; ++r) {
            const int g = r * 256 + tid;
            const int t = g >> 3, cb = g & 7;
            const float4 a = *(const float4*)&ft[t][cb * 8];
            const float4 bq = *(const float4*)&ft[t][cb * 8 + 4];
            f16x8 o = { (_Float16)a.x,  (_Float16)a.y,  (_Float16)a.z,  (_Float16)a.w,
                        (_Float16)bq.x, (_Float16)bq.y, (_Float16)bq.z, (_Float16)bq.w };
            *(f16x8*)(dst + (size_t)t * 64 + (size_t)(cb ^ (t & 7)) * 8) = o;
        }
    } else {
        _Float16* dst = ws + (size_t)MAT_HALVES + (size_t)head * 65536;
#pragma unroll
        for (int i = 0; i < 4; ++i) {
            const int c = i * 16 + (tid >> 4);
            const int s = (tid & 15) * 4;
            const float4 v = *(const float4*)(src + (size_t)c * 1024 + s0 + s);
            f16x4 o = { (_Float16)v.x, (_Float16)v.y, (_Float16)v.z, (_Float16)v.w };
            const int sb = s >> 3, pos = s & 7;
            *(f16x4*)(dst + (size_t)c * 1024 + s0 + (size_t)((sb ^ (c & 7)) * 8 + pos)) = o;
        }
    }
}

// ---------------- Main flash kernel: 16 waves, s-split, dbuf K/V -------------
__launch_bounds__(1024, 8)
__global__ void attn_kernel(const float* __restrict__ qkv,
                            const _Float16* __restrict__ ws,
                            float* __restrict__ out) {
    // m.kv[buf]: K [64 s][64 c] at halves 0..4095, V [64 c][64 s] at 4096..8191.
    // m.ft: Q transpose staging (prologue). ep: s-half merge (epilogue).
    __shared__ __align__(16) union SM {
        struct { _Float16 kv[2][8192]; float ft[64][68]; } m;   // 49.4 KB
        struct { float z[4][64][33]; float ps[4][64][2]; } ep;  // 35.8 KB
    } sm;

    const int tid  = threadIdx.x;
    const int wv   = tid >> 6;        // 0..15
    const int tg   = wv & 7;          // t-group: rows tg*32..tg*32+31
    const int sg   = wv >> 3;         // s-half: ns in {sg*2, sg*2+1}
    const int lane = tid & 63;
    const int li   = lane & 15;
    const int quad = lane >> 4;

    const int bid  = blockIdx.x;
    const int head = (bid >> 5) * 8 + (bid & 7);  // head's 4 t-tiles share an XCD
    const int tt   = (bid >> 3) & 3;
    const int t0   = tt * 256;

    const int b = head >> 4, h = head & 15;
    const float* qsrc = qkv + (size_t)b * 3072 * 1024 + (size_t)(h * 64) * 1024;
    const _Float16* kt = ws + (size_t)head * 65536;
    const _Float16* vh = ws + (size_t)MAT_HALVES + (size_t)head * 65536;

    // ---- Prefetch tiles 0,1: sg0 waves load K, sg1 waves load V ----
    const int g = tg * 64 + lane;     // 0..511 within the half
#pragma unroll
    for (int u = 0; u < 2; ++u) {
        if (sg == 0) {
            ASYNC16(kt + (size_t)u * 4096 + (size_t)g * 8, &sm.m.kv[u][g * 8]);
        } else {
            ASYNC16(vh + (size_t)(g >> 3) * 1024 + u * 64 + (size_t)(g & 7) * 8,
                    &sm.m.kv[u][4096 + g * 8]);
        }
    }

    // ---- Q prologue: 4 chunks of 64 t, fp32 LDS transpose -> bqf regs ----
    const float qscale = 0.125f * 1.44269504f;
    f16x8 bqf[2][2];
    {
        const int ci  = tid >> 4;         // 0..63
        const int tq4 = (tid & 15) * 4;
        for (int ct = 0; ct < 4; ++ct) {
            const float4 v = *(const float4*)(qsrc + (size_t)ci * 1024 + t0 + ct * 64 + tq4);
            sm.m.ft[tq4 + 0][ci] = v.x * qscale;
            sm.m.ft[tq4 + 1][ci] = v.y * qscale;
            sm.m.ft[tq4 + 2][ci] = v.z * qscale;
            sm.m.ft[tq4 + 3][ci] = v.w * qscale;
            __syncthreads();
            if ((tg >> 1) == ct) {
#pragma unroll
                for (int sub = 0; sub < 2; ++sub) {
                    const int tl = (tg & 1) * 32 + sub * 16 + li;
#pragma unroll
                    for (int kk = 0; kk < 2; ++kk) {
                        const int c0 = (kk * 4 + quad) * 8;
                        const float4 a  = *(const float4*)&sm.m.ft[tl][c0];
                        const float4 b2 = *(const float4*)&sm.m.ft[tl][c0 + 4];
                        bqf[sub][kk] = f16x8{ (_Float16)a.x,  (_Float16)a.y,
                                              (_Float16)a.z,  (_Float16)a.w,
                                              (_Float16)b2.x, (_Float16)b2.y,
                                              (_Float16)b2.z, (_Float16)b2.w };
                    }
                }
            }
            __syncthreads();
        }
    }

    f32x4 accz[2][4] = {};       // [sub][nc], partial over this wave's s-half
    float psum[2] = {};

    // ---- Main loop: 16 s-tiles, dbuf, 1 barrier/iter ----
    for (int si = 0; si < 16; ++si) {
        __syncthreads();  // buf[si&1] loads drained; prior reads of other buf done
        if (si < 15) {
            const int s0n = (si + 1) * 64;
            const int nb  = (si + 1) & 1;
            if (sg == 0) {
                ASYNC16(kt + (size_t)s0n * 64 + (size_t)g * 8, &sm.m.kv[nb][g * 8]);
            } else {
                ASYNC16(vh + (size_t)(g >> 3) * 1024 + s0n + (size_t)(g & 7) * 8,
                        &sm.m.kv[nb][4096 + g * 8]);
            }
        }
        const _Float16* Kl = &sm.m.kv[si & 1][0];
        const _Float16* Vl = &sm.m.kv[si & 1][4096];

        __builtin_amdgcn_s_setprio(1);
#pragma unroll
        for (int n2 = 0; n2 < 2; ++n2) {
            const int ns = sg * 2 + n2;
            // S^T = K Q^T for this 16-s strip (k=64 via 2 x mfma 16x16x32)
            f16x8 ak[2];
#pragma unroll
            for (int kk = 0; kk < 2; ++kk) {
                const int cb = (kk * 4 + quad) ^ (li & 7);
                ak[kk] = *(const f16x8*)&Kl[(ns * 16 + li) * 64 + cb * 8];
            }
            f16x4 pk[2];
#pragma unroll
            for (int sub = 0; sub < 2; ++sub) {
                f32x4 st = {};
                st = __builtin_amdgcn_mfma_f32_16x16x32_f16(ak[0], bqf[sub][0], st, 0, 0, 0);
                st = __builtin_amdgcn_mfma_f32_16x16x32_f16(ak[1], bqf[sub][1], st, 0, 0, 0);
                const float p0 = __builtin_amdgcn_exp2f(st[0]);
                const float p1 = __builtin_amdgcn_exp2f(st[1]);
                const float p2 = __builtin_amdgcn_exp2f(st[2]);
                const float p3 = __builtin_amdgcn_exp2f(st[3]);
                psum[sub] += (p0 + p1) + (p2 + p3);
                pk[sub] = f16x4{ (_Float16)p0, (_Float16)p1,
                                 (_Float16)p2, (_Float16)p3 };
            }
            // Z^T += P V^T for this strip: pk IS the 16x16x16 A-operand.
            const int sb  = 2 * ns + (quad >> 1);
            const int pos = (quad & 1) * 4;
#pragma unroll
            for (int nc = 0; nc < 4; ++nc) {
                const int c = nc * 16 + li;
                f16x4 bv = *(const f16x4*)&Vl[c * 64 + ((sb ^ (c & 7)) << 3) + pos];
                accz[0][nc] = __builtin_amdgcn_mfma_f32_16x16x16f16(
                    pk[0], bv, accz[0][nc], 0, 0, 0);
                accz[1][nc] = __builtin_amdgcn_mfma_f32_16x16x16f16(
                    pk[1], bv, accz[1][nc], 0, 0, 0);
            }
        }
        __builtin_amdgcn_s_setprio(0);
    }

    // ---- Epilogue: merge the two s-halves, 2 phases of 4 t-groups ----
    float* obase = out + (size_t)b * 1024 * 1024
                       + (size_t)(h * 64) * 1024 + t0;
    __syncthreads();   // all loop reads of kv done; safe to overlay ep
#pragma unroll
    for (int ph = 0; ph < 2; ++ph) {
        if (sg == 1 && (tg >> 2) == ph) {
            const int tz = tg & 3;
#pragma unroll
            for (int sub = 0; sub < 2; ++sub)
#pragma unroll
                for (int nc = 0; nc < 4; ++nc)
                    *(f32x4*)&sm.ep.z[tz][lane][sub * 16 + nc * 4] = accz[sub][nc];
            sm.ep.ps[tz][lane][0] = psum[0];
            sm.ep.ps[tz][lane][1] = psum[1];
        }
        __syncthreads();
        if (sg == 0 && (tg >> 2) == ph) {
            const int tz = tg & 3;
            psum[0] += sm.ep.ps[tz][lane][0];
            psum[1] += sm.ep.ps[tz][lane][1];
#pragma unroll
            for (int sub = 0; sub < 2; ++sub)
#pragma unroll
                for (int nc = 0; nc < 4; ++nc) {
                    const f32x4 zp = *(const f32x4*)&sm.ep.z[tz][lane][sub * 16 + nc * 4];
                    accz[sub][nc] += zp;
                }
            // Denominators: cross-quad reduce + redistribute
            float rl[2][4];
#pragma unroll
            for (int sub = 0; sub < 2; ++sub) {
                float s = psum[sub];
                s += __shfl_xor(s, 16);
                s += __shfl_xor(s, 32);
#pragma unroll
                for (int r = 0; r < 4; ++r)
                    rl[sub][r] = 1.0f / __shfl(s, quad * 4 + r);
            }
            // Store: D^T rows contiguous in t -> direct float4 stores
#pragma unroll
            for (int sub = 0; sub < 2; ++sub)
#pragma unroll
                for (int nc = 0; nc < 4; ++nc) {
                    const int c = nc * 16 + li;
                    const int t = tg * 32 + sub * 16 + quad * 4;
                    f32x4 z = accz[sub][nc];
                    float4 o = { z[0] * rl[sub][0], z[1] * rl[sub][1],
                                 z[2] * rl[sub][2], z[3] * rl[sub][3] };
                    *(float4*)(obase + (size_t)c * 1024 + t) = o;
                }
        }
        __syncthreads();
    }
}

// ---------------- Fallback (single-kernel path, ws too small) ----------------
struct S1fb {
    _Float16 K[64][72];
    _Float16 V[64][72];
    _Float16 P[128][72];
};
union SMemFb {
    S1fb s1;
    float zt[64][132];
};

__launch_bounds__(256, 4)
__global__ void qkv_attn_fallback(const float* __restrict__ qkv,
                                  float* __restrict__ out) {
    constexpr int L = 1024;
    __shared__ SMemFb sm;
    const int tid  = threadIdx.x;
    const int wv   = tid >> 6;
    const int lane = tid & 63;
    const int li   = lane & 15;
    const int quad = lane >> 4;
    const int bid  = blockIdx.x;
    const int head = (bid >> 6) * 8 + (bid & 7);
    const int tt   = (bid >> 3) & 7;
    const int b = head >> 4;
    const int h = head & 15;
    const float* qbase = qkv + (size_t)b * 3072 * L + (size_t)(h * 64) * L;
    const float* kbase = qbase + (size_t)1024 * L;
    const float* vbase = qbase + (size_t)2048 * L;
    float*       obase = out + (size_t)b * 1024 * L + (size_t)(h * 64) * L;
    const int t0 = tt * 128;
#pragma unroll
    for (int i = 0; i < 4; ++i) {
        const int c = i * 16 + (tid >> 4);
        const int t = (tid & 15) * 8;
        const float4 qa = *(const float4*)(qbase + (size_t)c * L + t0 + t);
        const float4 qb = *(const float4*)(qbase + (size_t)c * L + t0 + t + 4);
        sm.s1.P[t + 0][c] = (_Float16)(qa.x * 0.125f);
        sm.s1.P[t + 1][c] = (_Float16)(qa.y * 0.125f);
        sm.s1.P[t + 2][c] = (_Float16)(qa.z * 0.125f);
        sm.s1.P[t + 3][c] = (_Float16)(qa.w * 0.125f);
        sm.s1.P[t + 4][c] = (_Float16)(qb.x * 0.125f);
        sm.s1.P[t + 5][c] = (_Float16)(qb.y * 0.125f);
        sm.s1.P[t + 6][c] = (_Float16)(qb.z * 0.125f);
        sm.s1.P[t + 7][c] = (_Float16)(qb.w * 0.125f);
    }
    __syncthreads();
    f16x8 aq0[2], aq1[2];
#pragma unroll
    for (int kk = 0; kk < 2; ++kk) {
        aq0[kk] = *(const f16x8*)&sm.s1.P[wv * 32 + li][kk * 32 + quad * 8];
        aq1[kk] = *(const f16x8*)&sm.s1.P[wv * 32 + 16 + li][kk * 32 + quad * 8];
    }
    f32x4 accz0[4] = {}, accz1[4] = {};
    float psum0[4] = {}, psum1[4] = {};
    float4 kreg[4], vreg[4];
#pragma unroll
    for (int i = 0; i < 4; ++i) {
        const int c = i * 16 + (tid >> 4);
        const int s = (tid & 15) * 4;
        kreg[i] = *(const float4*)(kbase + (size_t)c * L + s);
        vreg[i] = *(const float4*)(vbase + (size_t)c * L + s);
    }
    for (int si = 0; si < 16; ++si) {
        __syncthreads();
#pragma unroll
        for (int i = 0; i < 4; ++i) {
            const int c = i * 16 + (tid >> 4);
            const int s = (tid & 15) * 4;
            sm.s1.K[s + 0][c] = (_Float16)kreg[i].x;
            sm.s1.K[s + 1][c] = (_Float16)kreg[i].y;
            sm.s1.K[s + 2][c] = (_Float16)kreg[i].z;
            sm.s1.K[s + 3][c] = (_Float16)kreg[i].w;
            f16x4 pv = { (_Float16)vreg[i].x, (_Float16)vreg[i].y,
                         (_Float16)vreg[i].z, (_Float16)vreg[i].w };
            *(f16x4*)&sm.s1.V[c][s] = pv;
        }
        __syncthreads();
        if (si < 15) {
            const int s0n = (si + 1) * 64;
#pragma unroll
            for (int i = 0; i < 4; ++i) {
                const int c = i * 16 + (tid >> 4);
                const int s = (tid & 15) * 4;
                kreg[i] = *(const float4*)(kbase + (size_t)c * L + s0n + s);
                vreg[i] = *(const float4*)(vbase + (size_t)c * L + s0n + s);
            }
        }
#pragma unroll
        for (int nt = 0; nt < 4; ++nt) {
            f32x4 a0 = {}, a1 = {};
#pragma unroll
            for (int kk = 0; kk < 2; ++kk) {
                f16x8 bk = *(const f16x8*)&sm.s1.K[nt * 16 + li][kk * 32 + quad * 8];
                a0 = __builtin_amdgcn_mfma_f32_16x16x32_f16(aq0[kk], bk, a0, 0, 0, 0);
                a1 = __builtin_amdgcn_mfma_f32_16x16x32_f16(aq1[kk], bk, a1, 0, 0, 0);
            }
#pragma unroll
            for (int r = 0; r < 4; ++r) {
                const float p0 = __expf(a0[r]);
                const float p1 = __expf(a1[r]);
                psum0[r] += p0;
                psum1[r] += p1;
                sm.s1.P[wv * 32 + quad * 4 + r][nt * 16 + li] = (_Float16)p0;
                sm.s1.P[wv * 32 + 16 + quad * 4 + r][nt * 16 + li] = (_Float16)p1;
            }
        }
#pragma unroll
        for (int kk = 0; kk < 2; ++kk) {
            f16x8 ap0 = *(const f16x8*)&sm.s1.P[wv * 32 + li][kk * 32 + quad * 8];
            f16x8 ap1 = *(const f16x8*)&sm.s1.P[wv * 32 + 16 + li][kk * 32 + quad * 8];
#pragma unroll
            for (int nt = 0; nt < 4; ++nt) {
                f16x8 bv = *(const f16x8*)&sm.s1.V[nt * 16 + li][kk * 32 + quad * 8];
                accz0[nt] = __builtin_amdgcn_mfma_f32_16x16x32_f16(ap0, bv, accz0[nt], 0, 0, 0);
                accz1[nt] = __builtin_amdgcn_mfma_f32_16x16x32_f16(ap1, bv, accz1[nt], 0, 0, 0);
            }
        }
    }
    float rl0[4], rl1[4];
#pragma unroll
    for (int r = 0; r < 4; ++r) {
        float s0 = psum0[r], s1 = psum1[r];
        s0 += __shfl_xor(s0, 1); s0 += __shfl_xor(s0, 2);
        s0 += __shfl_xor(s0, 4); s0 += __shfl_xor(s0, 8);
        s1 += __shfl_xor(s1, 1); s1 += __shfl_xor(s1, 2);
        s1 += __shfl_xor(s1, 4); s1 += __shfl_xor(s1, 8);
        rl0[r] = 1.0f / s0;
        rl1[r] = 1.0f / s1;
    }
    __syncthreads();
#pragma unroll
    for (int nt = 0; nt < 4; ++nt)
#pragma unroll
        for (int r = 0; r < 4; ++r) {
            sm.zt[nt * 16 + li][wv * 32 + quad * 4 + r]      = accz0[nt][r] * rl0[r];
            sm.zt[nt * 16 + li][wv * 32 + 16 + quad * 4 + r] = accz1[nt][r] * rl1[r];
        }
    __syncthreads();
#pragma unroll
    for (int i = 0; i < 8; ++i) {
        const int c = i * 8 + (tid >> 5);
        const int t = (tid & 31) * 4;
        float4 o = { sm.zt[c][t], sm.zt[c][t + 1],
                     sm.zt[c][t + 2], sm.zt[c][t + 3] };
        *(float4*)(obase + (size_t)c * L + t0 + t) = o;
    }
}

extern "C" void kernel_launch(void* const* d_in, const int* in_sizes, int n_in,
                              void* d_out, int out_size, void* d_ws, size_t ws_size,
                              hipStream_t stream) {
    const float* qkv = (const float*)d_in[0];
    float* out = (float*)d_out;
    if (ws_size >= (size_t)WS_BYTES) {
        _Float16* ws = (_Float16*)d_ws;
        prepass_kv<<<4096, 256, 0, stream>>>(qkv, ws);
        // 128 heads x 4 t-tiles of 256; 1024-thread blocks -> 2 blocks/CU,
        // 32 waves/CU = 8 waves/SIMD.
        attn_kernel<<<512, 1024, 0, stream>>>(qkv, ws, out);
    } else {
        qkv_attn_fallback<<<1024, 256, 0, stream>>>(qkv, out);
    }
}

// Round 12
// 199.825 us; speedup vs baseline: 2.0212x; 2.0212x over previous
//
#include <hip/hip_runtime.h>

// QKVAttention: qkv [8, 3072, 1024] fp32 -> out [8, 1024, 1024] fp32
// Prepass: K (transpose+swizzle) and V (convert+swizzle) fp16 to ws.
// Attn: 1024-thread blocks, 16 waves = 8 t-groups x 2 s-halves. Each wave:
// 32 t-rows (2 subs), HALF the s-strips per tile -> per-CU LDS traffic
// unchanged vs r6 but (if VGPR<=64) 8 waves/SIMD hide the QK->exp->PV chain.
// r11 lesson: __launch_bounds__(1024,8) forced VGPR=32 -> 1.1 GB scratch
// spill (FETCH/WRITE 592/555 MB, 273us). State needs ~60 VGPR; use (1024,4)
// so the cap (128) sits above need and the compiler can land at ~64.
// K+V LDS dbuf via global_load_lds, 1 barrier/iter. PV uses mfma_16x16x16
// (QK C-fragment feeds PV A-operand in registers). Epilogue merges s-halves
// via LDS (2 phases of 4 t-groups, padded [64][33]).
// r9 lesson: V must stay LDS-staged (direct L2 reads uncoalesced, 146us).

typedef __attribute__((ext_vector_type(8))) _Float16 f16x8;
typedef __attribute__((ext_vector_type(4))) _Float16 f16x4;
typedef __attribute__((ext_vector_type(4))) float f32x4;

#define MAT_HALVES 8388608   // 16 MB per matrix (128 heads * 64 * 1024 halves)
#define WS_BYTES   33554432  // K + V fp16

#define ASYNC16(g, l) __builtin_amdgcn_global_load_lds(                    \
    (__attribute__((address_space(1))) void*)(void*)(g),                   \
    (__attribute__((address_space(3))) void*)(void*)(l), 16, 0, 0)

// ---------------- Pre-pass: K transpose + V convert, fp32 -> fp16 ------------
// Kt [head][s][64c], chunk c' = cb ^ (s&7)
// Vh [head][c][1024s], within each 64-s tile chunk s' = sb ^ (c&7)
__global__ __launch_bounds__(256) void prepass_kv(
    const float* __restrict__ qkv, _Float16* __restrict__ ws) {
    __shared__ float ft[64][68];
    const int tid = threadIdx.x;
    const int bid = blockIdx.x;       // 4096 = 2 mats * 128 heads * 16 blocks
    const int mat = bid >> 11;        // 0 K, 1 V
    const int idx = bid & 2047;
    const int head = idx >> 4;
    const int blk  = idx & 15;
    const int b = head >> 4, h = head & 15;
    const float* src = qkv + (size_t)b * 3072 * 1024
                           + (size_t)((1 + mat) * 1024 + h * 64) * 1024;
    const int s0 = blk * 64;
    if (mat == 0) {
#pragma unroll
        for (int i = 0; i < 4; ++i) {
            const int c = i * 16 + (tid >> 4);
            const int s = (tid & 15) * 4;
            const float4 v = *(const float4*)(src + (size_t)c * 1024 + s0 + s);
            ft[s + 0][c] = v.x;
            ft[s + 1][c] = v.y;
            ft[s + 2][c] = v.z;
            ft[s + 3][c] = v.w;
        }
        __syncthreads();
        _Float16* dst = ws + (size_t)head * 65536 + (size_t)s0 * 64;
#pragma unroll
        for (int r = 0; r < 2; ++r) {
            const int g = r * 256 + tid;
            const int t = g >> 3, cb = g & 7;
            const float4 a = *(const float4*)&ft[t][cb * 8];
            const float4 bq = *(const float4*)&ft[t][cb * 8 + 4];
            f16x8 o = { (_Float16)a.x,  (_Float16)a.y,  (_Float16)a.z,  (_Float16)a.w,
                        (_Float16)bq.x, (_Float16)bq.y, (_Float16)bq.z, (_Float16)bq.w };
            *(f16x8*)(dst + (size_t)t * 64 + (size_t)(cb ^ (t & 7)) * 8) = o;
        }
    } else {
        _Float16* dst = ws + (size_t)MAT_HALVES + (size_t)head * 65536;
#pragma unroll
        for (int i = 0; i < 4; ++i) {
            const int c = i * 16 + (tid >> 4);
            const int s = (tid & 15) * 4;
            const float4 v = *(const float4*)(src + (size_t)c * 1024 + s0 + s);
            f16x4 o = { (_Float16)v.x, (_Float16)v.y, (_Float16)v.z, (_Float16)v.w };
            const int sb = s >> 3, pos = s & 7;
            *(f16x4*)(dst + (size_t)c * 1024 + s0 + (size_t)((sb ^ (c & 7)) * 8 + pos)) = o;
        }
    }
}

// ---------------- Main flash kernel: 16 waves, s-split, dbuf K/V -------------
__launch_bounds__(1024, 4)
__global__ void attn_kernel(const float* __restrict__ qkv,
                            const _Float16* __restrict__ ws,
                            float* __restrict__ out) {
    // m.kv[buf]: K [64 s][64 c] at halves 0..4095, V [64 c][64 s] at 4096..8191.
    // m.ft: Q transpose staging (prologue). ep: s-half merge (epilogue).
    __shared__ __align__(16) union SM {
        struct { _Float16 kv[2][8192]; float ft[64][68]; } m;   // 49.4 KB
        struct { float z[4][64][33]; float ps[4][64][2]; } ep;  // 35.8 KB
    } sm;

    const int tid  = threadIdx.x;
    const int wv   = tid >> 6;        // 0..15
    const int tg   = wv & 7;          // t-group: rows tg*32..tg*32+31
    const int sg   = wv >> 3;         // s-half: ns in {sg*2, sg*2+1}
    const int lane = tid & 63;
    const int li   = lane & 15;
    const int quad = lane >> 4;

    const int bid  = blockIdx.x;
    const int head = (bid >> 5) * 8 + (bid & 7);  // head's 4 t-tiles share an XCD
    const int tt   = (bid >> 3) & 3;
    const int t0   = tt * 256;

    const int b = head >> 4, h = head & 15;
    const float* qsrc = qkv + (size_t)b * 3072 * 1024 + (size_t)(h * 64) * 1024;
    const _Float16* kt = ws + (size_t)head * 65536;
    const _Float16* vh = ws + (size_t)MAT_HALVES + (size_t)head * 65536;

    // ---- Prefetch tiles 0,1: sg0 waves load K, sg1 waves load V ----
    const int g = tg * 64 + lane;     // 0..511 within the half
#pragma unroll
    for (int u = 0; u < 2; ++u) {
        if (sg == 0) {
            ASYNC16(kt + (size_t)u * 4096 + (size_t)g * 8, &sm.m.kv[u][g * 8]);
        } else {
            ASYNC16(vh + (size_t)(g >> 3) * 1024 + u * 64 + (size_t)(g & 7) * 8,
                    &sm.m.kv[u][4096 + g * 8]);
        }
    }

    // ---- Q prologue: 4 chunks of 64 t, fp32 LDS transpose -> bqf regs ----
    const float qscale = 0.125f * 1.44269504f;
    f16x8 bqf[2][2];
    {
        const int ci  = tid >> 4;         // 0..63
        const int tq4 = (tid & 15) * 4;
        for (int ct = 0; ct < 4; ++ct) {
            const float4 v = *(const float4*)(qsrc + (size_t)ci * 1024 + t0 + ct * 64 + tq4);
            sm.m.ft[tq4 + 0][ci] = v.x * qscale;
            sm.m.ft[tq4 + 1][ci] = v.y * qscale;
            sm.m.ft[tq4 + 2][ci] = v.z * qscale;
            sm.m.ft[tq4 + 3][ci] = v.w * qscale;
            __syncthreads();
            if ((tg >> 1) == ct) {
#pragma unroll
                for (int sub = 0; sub < 2; ++sub) {
                    const int tl = (tg & 1) * 32 + sub * 16 + li;
#pragma unroll
                    for (int kk = 0; kk < 2; ++kk) {
                        const int c0 = (kk * 4 + quad) * 8;
                        const float4 a  = *(const float4*)&sm.m.ft[tl][c0];
                        const float4 b2 = *(const float4*)&sm.m.ft[tl][c0 + 4];
                        bqf[sub][kk] = f16x8{ (_Float16)a.x,  (_Float16)a.y,
                                              (_Float16)a.z,  (_Float16)a.w,
                                              (_Float16)b2.x, (_Float16)b2.y,
                                              (_Float16)b2.z, (_Float16)b2.w };
                    }
                }
            }
            __syncthreads();
        }
    }

    f32x4 accz[2][4] = {};       // [sub][nc], partial over this wave's s-half
    float psum[2] = {};

    // ---- Main loop: 16 s-tiles, dbuf, 1 barrier/iter ----
    for (int si = 0; si < 16; ++si) {
        __syncthreads();  // buf[si&1] loads drained; prior reads of other buf done
        if (si < 15) {
            const int s0n = (si + 1) * 64;
            const int nb  = (si + 1) & 1;
            if (sg == 0) {
                ASYNC16(kt + (size_t)s0n * 64 + (size_t)g * 8, &sm.m.kv[nb][g * 8]);
            } else {
                ASYNC16(vh + (size_t)(g >> 3) * 1024 + s0n + (size_t)(g & 7) * 8,
                        &sm.m.kv[nb][4096 + g * 8]);
            }
        }
        const _Float16* Kl = &sm.m.kv[si & 1][0];
        const _Float16* Vl = &sm.m.kv[si & 1][4096];

        __builtin_amdgcn_s_setprio(1);
#pragma unroll
        for (int n2 = 0; n2 < 2; ++n2) {
            const int ns = sg * 2 + n2;
            // S^T = K Q^T for this 16-s strip (k=64 via 2 x mfma 16x16x32)
            f16x8 ak[2];
#pragma unroll
            for (int kk = 0; kk < 2; ++kk) {
                const int cb = (kk * 4 + quad) ^ (li & 7);
                ak[kk] = *(const f16x8*)&Kl[(ns * 16 + li) * 64 + cb * 8];
            }
            f16x4 pk[2];
#pragma unroll
            for (int sub = 0; sub < 2; ++sub) {
                f32x4 st = {};
                st = __builtin_amdgcn_mfma_f32_16x16x32_f16(ak[0], bqf[sub][0], st, 0, 0, 0);
                st = __builtin_amdgcn_mfma_f32_16x16x32_f16(ak[1], bqf[sub][1], st, 0, 0, 0);
                const float p0 = __builtin_amdgcn_exp2f(st[0]);
                const float p1 = __builtin_amdgcn_exp2f(st[1]);
                const float p2 = __builtin_amdgcn_exp2f(st[2]);
                const float p3 = __builtin_amdgcn_exp2f(st[3]);
                psum[sub] += (p0 + p1) + (p2 + p3);
                pk[sub] = f16x4{ (_Float16)p0, (_Float16)p1,
                                 (_Float16)p2, (_Float16)p3 };
            }
            // Z^T += P V^T for this strip: pk IS the 16x16x16 A-operand.
            const int sb  = 2 * ns + (quad >> 1);
            const int pos = (quad & 1) * 4;
#pragma unroll
            for (int nc = 0; nc < 4; ++nc) {
                const int c = nc * 16 + li;
                f16x4 bv = *(const f16x4*)&Vl[c * 64 + ((sb ^ (c & 7)) << 3) + pos];
                accz[0][nc] = __builtin_amdgcn_mfma_f32_16x16x16f16(
                    pk[0], bv, accz[0][nc], 0, 0, 0);
                accz[1][nc] = __builtin_amdgcn_mfma_f32_16x16x16f16(
                    pk[1], bv, accz[1][nc], 0, 0, 0);
            }
        }
        __builtin_amdgcn_s_setprio(0);
    }

    // ---- Epilogue: merge the two s-halves, 2 phases of 4 t-groups ----
    float* obase = out + (size_t)b * 1024 * 1024
                       + (size_t)(h * 64) * 1024 + t0;
    __syncthreads();   // all loop reads of kv done; safe to overlay ep
#pragma unroll
    for (int ph = 0; ph < 2; ++ph) {
        if (sg == 1 && (tg >> 2) == ph) {
            const int tz = tg & 3;
#pragma unroll
            for (int sub = 0; sub < 2; ++sub)
#pragma unroll
                for (int nc = 0; nc < 4; ++nc)
                    *(f32x4*)&sm.ep.z[tz][lane][sub * 16 + nc * 4] = accz[sub][nc];
            sm.ep.ps[tz][lane][0] = psum[0];
            sm.ep.ps[tz][lane][1] = psum[1];
        }
        __syncthreads();
        if (sg == 0 && (tg >> 2) == ph) {
            const int tz = tg & 3;
            psum[0] += sm.ep.ps[tz][lane][0];
            psum[1] += sm.ep.ps[tz][lane][1];
#pragma unroll
            for (int sub = 0; sub < 2; ++sub)
#pragma unroll
                for (int nc = 0; nc < 4; ++nc) {
                    const f32x4 zp = *(const f32x4*)&sm.ep.z[tz][lane][sub * 16 + nc * 4];
                    accz[sub][nc] += zp;
                }
            // Denominators: cross-quad reduce + redistribute
            float rl[2][4];
#pragma unroll
            for (int sub = 0; sub < 2; ++sub) {
                float s = psum[sub];
                s += __shfl_xor(s, 16);
                s += __shfl_xor(s, 32);
#pragma unroll
                for (int r = 0; r < 4; ++r)
                    rl[sub][r] = 1.0f / __shfl(s, quad * 4 + r);
            }
            // Store: D^T rows contiguous in t -> direct float4 stores
#pragma unroll
            for (int sub = 0; sub < 2; ++sub)
#pragma unroll
                for (int nc = 0; nc < 4; ++nc) {
                    const int c = nc * 16 + li;
                    const int t = tg * 32 + sub * 16 + quad * 4;
                    f32x4 z = accz[sub][nc];
                    float4 o = { z[0] * rl[sub][0], z[1] * rl[sub][1],
                                 z[2] * rl[sub][2], z[3] * rl[sub][3] };
                    *(float4*)(obase + (size_t)c * 1024 + t) = o;
                }
        }
        __syncthreads();
    }
}

// ---------------- Fallback (single-kernel path, ws too small) ----------------
struct S1fb {
    _Float16 K[64][72];
    _Float16 V[64][72];
    _Float16 P[128][72];
};
union SMemFb {
    S1fb s1;
    float zt[64][132];
};

__launch_bounds__(256, 4)
__global__ void qkv_attn_fallback(const float* __restrict__ qkv,
                                  float* __restrict__ out) {
    constexpr int L = 1024;
    __shared__ SMemFb sm;
    const int tid  = threadIdx.x;
    const int wv   = tid >> 6;
    const int lane = tid & 63;
    const int li   = lane & 15;
    const int quad = lane >> 4;
    const int bid  = blockIdx.x;
    const int head = (bid >> 6) * 8 + (bid & 7);
    const int tt   = (bid >> 3) & 7;
    const int b = head >> 4;
    const int h = head & 15;
    const float* qbase = qkv + (size_t)b * 3072 * L + (size_t)(h * 64) * L;
    const float* kbase = qbase + (size_t)1024 * L;
    const float* vbase = qbase + (size_t)2048 * L;
    float*       obase = out + (size_t)b * 1024 * L + (size_t)(h * 64) * L;
    const int t0 = tt * 128;
#pragma unroll
    for (int i = 0; i < 4; ++i) {
        const int c = i * 16 + (tid >> 4);
        const int t = (tid & 15) * 8;
        const float4 qa = *(const float4*)(qbase + (size_t)c * L + t0 + t);
        const float4 qb = *(const float4*)(qbase + (size_t)c * L + t0 + t + 4);
        sm.s1.P[t + 0][c] = (_Float16)(qa.x * 0.125f);
        sm.s1.P[t + 1][c] = (_Float16)(qa.y * 0.125f);
        sm.s1.P[t + 2][c] = (_Float16)(qa.z * 0.125f);
        sm.s1.P[t + 3][c] = (_Float16)(qa.w * 0.125f);
        sm.s1.P[t + 4][c] = (_Float16)(qb.x * 0.125f);
        sm.s1.P[t + 5][c] = (_Float16)(qb.y * 0.125f);
        sm.s1.P[t + 6][c] = (_Float16)(qb.z * 0.125f);
        sm.s1.P[t + 7][c] = (_Float16)(qb.w * 0.125f);
    }
    __syncthreads();
    f16x8 aq0[2], aq1[2];
#pragma unroll
    for (int kk = 0; kk < 2; ++kk) {
        aq0[kk] = *(const f16x8*)&sm.s1.P[wv * 32 + li][kk * 32 + quad * 8];
        aq1[kk] = *(const f16x8*)&sm.s1.P[wv * 32 + 16 + li][kk * 32 + quad * 8];
    }
    f32x4 accz0[4] = {}, accz1[4] = {};
    float psum0[4] = {}, psum1[4] = {};
    float4 kreg[4], vreg[4];
#pragma unroll
    for (int i = 0; i < 4; ++i) {
        const int c = i * 16 + (tid >> 4);
        const int s = (tid & 15) * 4;
        kreg[i] = *(const float4*)(kbase + (size_t)c * L + s);
        vreg[i] = *(const float4*)(vbase + (size_t)c * L + s);
    }
    for (int si = 0; si < 16; ++si) {
        __syncthreads();
#pragma unroll
        for (int i = 0; i < 4; ++i) {
            const int c = i * 16 + (tid >> 4);
            const int s = (tid & 15) * 4;
            sm.s1.K[s + 0][c] = (_Float16)kreg[i].x;
            sm.s1.K[s + 1][c] = (_Float16)kreg[i].y;
            sm.s1.K[s + 2][c] = (_Float16)kreg[i].z;
            sm.s1.K[s + 3][c] = (_Float16)kreg[i].w;
            f16x4 pv = { (_Float16)vreg[i].x, (_Float16)vreg[i].y,
                         (_Float16)vreg[i].z, (_Float16)vreg[i].w };
            *(f16x4*)&sm.s1.V[c][s] = pv;
        }
        __syncthreads();
        if (si < 15) {
            const int s0n = (si + 1) * 64;
#pragma unroll
            for (int i = 0; i < 4; ++i) {
                const int c = i * 16 + (tid >> 4);
                const int s = (tid & 15) * 4;
                kreg[i] = *(const float4*)(kbase + (size_t)c * L + s0n + s);
                vreg[i] = *(const float4*)(vbase + (size_t)c * L + s0n + s);
            }
        }
#pragma unroll
        for (int nt = 0; nt < 4; ++nt) {
            f32x4 a0 = {}, a1 = {};
#pragma unroll
            for (int kk = 0; kk < 2; ++kk) {
                f16x8 bk = *(const f16x8*)&sm.s1.K[nt * 16 + li][kk * 32 + quad * 8];
                a0 = __builtin_amdgcn_mfma_f32_16x16x32_f16(aq0[kk], bk, a0, 0, 0, 0);
                a1 = __builtin_amdgcn_mfma_f32_16x16x32_f16(aq1[kk], bk, a1, 0, 0, 0);
            }
#pragma unroll
            for (int r = 0; r < 4; ++r) {
                const float p0 = __expf(a0[r]);
                const float p1 = __expf(a1[r]);
                psum0[r] += p0;
                psum1[r] += p1;
                sm.s1.P[wv * 32 + quad * 4 + r][nt * 16 + li] = (_Float16)p0;
                sm.s1.P[wv * 32 + 16 + quad * 4 + r][nt * 16 + li] = (_Float16)p1;
            }
        }
#pragma unroll
        for (int kk = 0; kk < 2; ++kk) {
            f16x8 ap0 = *(const f16x8*)&sm.s1.P[wv * 32 + li][kk * 32 + quad * 8];
            f16x8 ap1 = *(const f16x8*)&sm.s1.P[wv * 32 + 16 + li][kk * 32 + quad * 8];
#pragma unroll
            for (int nt = 0; nt < 4; ++nt) {
                f16x8 bv = *(const f16x8*)&sm.s1.V[nt * 16 + li][kk * 32 + quad * 8];
                accz0[nt] = __builtin_amdgcn_mfma_f32_16x16x32_f16(ap0, bv, accz0[nt], 0, 0, 0);
                accz1[nt] = __builtin_amdgcn_mfma_f32_16x16x32_f16(ap1, bv, accz1[nt], 0, 0, 0);
            }
        }
    }
    float rl0[4], rl1[4];
#pragma unroll
    for (int r = 0; r < 4; ++r) {
        float s0 = psum0[r], s1 = psum1[r];
        s0 += __shfl_xor(s0, 1); s0 += __shfl_xor(s0, 2);
        s0 += __shfl_xor(s0, 4); s0 += __shfl_xor(s0, 8);
        s1 += __shfl_xor(s1, 1); s1 += __shfl_xor(s1, 2);
        s1 += __shfl_xor(s1, 4); s1 += __shfl_xor(s1, 8);
        rl0[r] = 1.0f / s0;
        rl1[r] = 1.0f / s1;
    }
    __syncthreads();
#pragma unroll
    for (int nt = 0; nt < 4; ++nt)
#pragma unroll
        for (int r = 0; r < 4; ++r) {
            sm.zt[nt * 16 + li][wv * 32 + quad * 4 + r]      = accz0[nt][r] * rl0[r];
            sm.zt[nt * 16 + li][wv * 32 + 16 + quad * 4 + r] = accz1[nt][r] * rl1[r];
        }
    __syncthreads();
#pragma unroll
    for (int i = 0; i < 8; ++i) {
        const int c = i * 8 + (tid >> 5);
        const int t = (tid & 31) * 4;
        float4 o = { sm.zt[c][t], sm.zt[c][t + 1],
                     sm.zt[c][t + 2], sm.zt[c][t + 3] };
        *(float4*)(obase + (size_t)c * L + t0 + t) = o;
    }
}

extern "C" void kernel_launch(void* const* d_in, const int* in_sizes, int n_in,
                              void* d_out, int out_size, void* d_ws, size_t ws_size,
                              hipStream_t stream) {
    const float* qkv = (const float*)d_in[0];
    float* out = (float*)d_out;
    if (ws_size >= (size_t)WS_BYTES) {
        _Float16* ws = (_Float16*)d_ws;
        prepass_kv<<<4096, 256, 0, stream>>>(qkv, ws);
        // 128 heads x 4 t-tiles of 256; 1024-thread blocks; if VGPR<=64 both
        // blocks/CU co-reside -> 32 waves/CU = 8 waves/SIMD.
        attn_kernel<<<512, 1024, 0, stream>>>(qkv, ws, out);
    } else {
        qkv_attn_fallback<<<1024, 256, 0, stream>>>(qkv, out);
    }
}

// Round 14
// 191.873 us; speedup vs baseline: 2.1050x; 1.0414x over previous
//
#include <hip/hip_runtime.h>

// QKVAttention: qkv [8, 3072, 1024] fp32 -> out [8, 1024, 1024] fp32
// Prepass: K (transpose+swizzle) and V (convert+swizzle) fp16 to ws (unchanged).
// Attn: 512-thread blocks (8 waves x 32 t-rows), t-tile 256, 2-buf K/V via
// global_load_lds, 1 barrier/iter. r13 RESTRUCTURE: 32x32x16 MFMA throughout.
// QK: st(32s x 32t) = sum_kc mfma(K-frag, Q-frag). exp2 on f32x16 C-frag.
// P stays in registers: pack f16 pairs + permlane32_swap assembles PV's
// B-operand (col=t,k=s) directly; PV: accz = mfma(V-frag, P-frag, accz).
// 16 MFMA/wave-tile (was 48: 16 QK + 32 tiny 16x16x16 PV). Denominator:
// psum + shfl_xor(,32) -> rl; both lanes of a t-column hold it natively.
// r12 falsified occupancy theory (8 w/SIMD, VGPR 52 -> still 67us @33%);
// plateau is instruction-stream cost, hence this rewrite.
// r9: V stays LDS-staged. r4/r11: no tight launch_bounds (spill).

typedef __attribute__((ext_vector_type(8)))  _Float16 f16x8;
typedef __attribute__((ext_vector_type(4)))  _Float16 f16x4;
typedef __attribute__((ext_vector_type(4)))  float    f32x4;
typedef __attribute__((ext_vector_type(16))) float    f32x16;
typedef __attribute__((ext_vector_type(2)))  int      i32x2;
typedef __attribute__((ext_vector_type(4)))  int      i32x4;

#define MAT_HALVES 8388608   // 16 MB per matrix (128 heads * 64 * 1024 halves)
#define WS_BYTES   33554432  // K + V fp16

#define ASYNC16(g, l) __builtin_amdgcn_global_load_lds(                    \
    (__attribute__((address_space(1))) void*)(void*)(g),                   \
    (__attribute__((address_space(3))) void*)(void*)(l), 16, 0, 0)

static __device__ __forceinline__ int pack2(float x, float y) {
    union { _Float16 h[2]; int i; } u;
    u.h[0] = (_Float16)x;
    u.h[1] = (_Float16)y;
    return u.i;
}

// ---------------- Pre-pass: K transpose + V convert, fp32 -> fp16 ------------
// Kt [head][s][64c], chunk c' = cb ^ (s&7)
// Vh [head][c][1024s], within each 64-s tile chunk s' = sb ^ (c&7)
__global__ __launch_bounds__(256) void prepass_kv(
    const float* __restrict__ qkv, _Float16* __restrict__ ws) {
    __shared__ float ft[64][68];
    const int tid = threadIdx.x;
    const int bid = blockIdx.x;       // 4096 = 2 mats * 128 heads * 16 blocks
    const int mat = bid >> 11;        // 0 K, 1 V
    const int idx = bid & 2047;
    const int head = idx >> 4;
    const int blk  = idx & 15;
    const int b = head >> 4, h = head & 15;
    const float* src = qkv + (size_t)b * 3072 * 1024
                           + (size_t)((1 + mat) * 1024 + h * 64) * 1024;
    const int s0 = blk * 64;
    if (mat == 0) {
#pragma unroll
        for (int i = 0; i < 4; ++i) {
            const int c = i * 16 + (tid >> 4);
            const int s = (tid & 15) * 4;
            const float4 v = *(const float4*)(src + (size_t)c * 1024 + s0 + s);
            ft[s + 0][c] = v.x;
            ft[s + 1][c] = v.y;
            ft[s + 2][c] = v.z;
            ft[s + 3][c] = v.w;
        }
        __syncthreads();
        _Float16* dst = ws + (size_t)head * 65536 + (size_t)s0 * 64;
#pragma unroll
        for (int r = 0; r < 2; ++r) {
            const int g = r * 256 + tid;
            const int t = g >> 3, cb = g & 7;
            const float4 a = *(const float4*)&ft[t][cb * 8];
            const float4 bq = *(const float4*)&ft[t][cb * 8 + 4];
            f16x8 o = { (_Float16)a.x,  (_Float16)a.y,  (_Float16)a.z,  (_Float16)a.w,
                        (_Float16)bq.x, (_Float16)bq.y, (_Float16)bq.z, (_Float16)bq.w };
            *(f16x8*)(dst + (size_t)t * 64 + (size_t)(cb ^ (t & 7)) * 8) = o;
        }
    } else {
        _Float16* dst = ws + (size_t)MAT_HALVES + (size_t)head * 65536;
#pragma unroll
        for (int i = 0; i < 4; ++i) {
            const int c = i * 16 + (tid >> 4);
            const int s = (tid & 15) * 4;
            const float4 v = *(const float4*)(src + (size_t)c * 1024 + s0 + s);
            f16x4 o = { (_Float16)v.x, (_Float16)v.y, (_Float16)v.z, (_Float16)v.w };
            const int sb = s >> 3, pos = s & 7;
            *(f16x4*)(dst + (size_t)c * 1024 + s0 + (size_t)((sb ^ (c & 7)) * 8 + pos)) = o;
        }
    }
}

// ---------------- Main flash kernel: 8 waves, 32x32 MFMA, reg-P --------------
__launch_bounds__(512, 2)
__global__ void attn_kernel(const float* __restrict__ qkv,
                            const _Float16* __restrict__ ws,
                            float* __restrict__ out) {
    __shared__ __align__(16) _Float16 kv[2][8192];   // K 0..4095, V 4096..8191
    __shared__ __align__(16) float ft[64][68];       // Q transpose (prologue)

    const int tid  = threadIdx.x;
    const int wv   = tid >> 6;        // 0..7
    const int lane = tid & 63;
    const int l31  = lane & 31;
    const int lh   = lane >> 5;       // lane half
    const int l7   = l31 & 7;

    const int bid  = blockIdx.x;
    const int head = (bid >> 5) * 8 + (bid & 7);  // head's 4 t-tiles share an XCD
    const int tt   = (bid >> 3) & 3;
    const int t0   = tt * 256;

    const int b = head >> 4, h = head & 15;
    const float* qsrc = qkv + (size_t)b * 3072 * 1024 + (size_t)(h * 64) * 1024;
    const _Float16* kt = ws + (size_t)head * 65536;
    const _Float16* vh = ws + (size_t)MAT_HALVES + (size_t)head * 65536;

    // ---- Prefetch tiles 0,1 into kv[0],kv[1] (overlaps Q prologue) ----
    ASYNC16(kt + (size_t)tid * 8, &kv[0][tid * 8]);
    ASYNC16(kt + (size_t)4096 + (size_t)tid * 8, &kv[1][tid * 8]);
    ASYNC16(vh + (size_t)(tid >> 3) * 1024 + (size_t)(tid & 7) * 8,
            &kv[0][4096 + tid * 8]);
    ASYNC16(vh + (size_t)(tid >> 3) * 1024 + 64 + (size_t)(tid & 7) * 8,
            &kv[1][4096 + tid * 8]);

    // ---- Q prologue: 4 rounds of 64 t, fp32 LDS transpose -> bqf[4] ----
    // bqf[kc]: B-frag of 32x32x16 QK: col t = wave_base + l31, k=c = 16kc+8lh+i
    const float qscale = 0.125f * 1.44269504f;
    f16x8 bqf[4];
    {
        const int ci = tid >> 4;          // 0..31
        const int tq = (tid & 15) * 4;
        for (int ct = 0; ct < 4; ++ct) {
#pragma unroll
            for (int i = 0; i < 2; ++i) {
                const int c = i * 32 + ci;
                const float4 v = *(const float4*)(qsrc + (size_t)c * 1024 + t0 + ct * 64 + tq);
                ft[tq + 0][c] = v.x * qscale;
                ft[tq + 1][c] = v.y * qscale;
                ft[tq + 2][c] = v.z * qscale;
                ft[tq + 3][c] = v.w * qscale;
            }
            __syncthreads();
            if ((wv >> 1) == ct) {
                const int tl = (wv & 1) * 32 + l31;
#pragma unroll
                for (int kc = 0; kc < 4; ++kc) {
                    const int c0 = (2 * kc + lh) * 8;
                    const float4 a  = *(const float4*)&ft[tl][c0];
                    const float4 b2 = *(const float4*)&ft[tl][c0 + 4];
                    bqf[kc] = f16x8{ (_Float16)a.x,  (_Float16)a.y,
                                     (_Float16)a.z,  (_Float16)a.w,
                                     (_Float16)b2.x, (_Float16)b2.y,
                                     (_Float16)b2.z, (_Float16)b2.w };
                }
            }
            __syncthreads();
        }
    }

    f32x16 accz[2] = {};   // [cblk]: Z^T frag, col t = l31, rows c
    float psum = 0.0f;

    // ---- Main loop: 16 s-tiles, dbuf, 1 barrier/iter ----
    for (int si = 0; si < 16; ++si) {
        __syncthreads();  // buf[si&1] loads drained; prior reads of other buf done
        if (si < 15) {
            const int s0n = (si + 1) * 64;
            const int nb  = (si + 1) & 1;
            ASYNC16(kt + (size_t)s0n * 64 + (size_t)tid * 8, &kv[nb][tid * 8]);
            ASYNC16(vh + (size_t)(tid >> 3) * 1024 + s0n + (size_t)(tid & 7) * 8,
                    &kv[nb][4096 + tid * 8]);
        }
        const _Float16* Kl = &kv[si & 1][0];
        const _Float16* Vl = &kv[si & 1][4096];

        __builtin_amdgcn_s_setprio(1);
#pragma unroll
        for (int sblk = 0; sblk < 2; ++sblk) {
            // ---- S^T(32s x 32t) = K Q^T, k=c=64 via 4 x mfma 32x32x16 ----
            const int r = sblk * 32 + l31;    // K row s (A row = l31)
            f32x16 st = {};
#pragma unroll
            for (int kc = 0; kc < 4; ++kc) {
                f16x8 ak = *(const f16x8*)&Kl[r * 64 + (((2 * kc + lh) ^ l7) << 3)];
                st = __builtin_amdgcn_mfma_f32_32x32x16_f16(ak, bqf[kc], st, 0, 0, 0);
            }
            // ---- exp2 + psum (col t = l31 for every reg) ----
            float p[16];
#pragma unroll
            for (int i = 0; i < 16; ++i) {
                p[i] = __builtin_amdgcn_exp2f(st[i]);
                psum += p[i];
            }
            // ---- pack P -> PV B-frags via permlane32_swap; PV MFMA ----
#pragma unroll
            for (int kc2 = 0; kc2 < 2; ++kc2) {
                const int g = kc2 * 8;
                const int a0 = pack2(p[g + 0], p[g + 1]);
                const int a1 = pack2(p[g + 2], p[g + 3]);
                const int b0 = pack2(p[g + 4], p[g + 5]);
                const int b1 = pack2(p[g + 6], p[g + 7]);
                i32x2 s0 = __builtin_amdgcn_permlane32_swap(a0, b0, false, false);
                i32x2 s1 = __builtin_amdgcn_permlane32_swap(a1, b1, false, false);
                union { i32x4 w; f16x8 f; } u;
                u.w = i32x4{ s0[0], s1[0], s0[1], s1[1] };
                const f16x8 pb = u.f;     // B-frag: col=t=l31, k=s=16kc2+8lh+i
                const int sc = 4 * sblk + 2 * kc2 + lh;   // s-chunk for V read
#pragma unroll
                for (int cblk = 0; cblk < 2; ++cblk) {
                    const int c = cblk * 32 + l31;
                    f16x8 av = *(const f16x8*)&Vl[c * 64 + ((sc ^ l7) << 3)];
                    accz[cblk] = __builtin_amdgcn_mfma_f32_32x32x16_f16(
                        av, pb, accz[cblk], 0, 0, 0);
                }
            }
        }
        __builtin_amdgcn_s_setprio(0);
    }

    // ---- Denominator: lanes t and t+32 both hold partial psum(t) ----
    psum += __shfl_xor(psum, 32);
    const float rl = 1.0f / psum;

    // ---- Store: Z^T[c][t], col t = l31 -> lane-contiguous in t ----
    float* obase = out + (size_t)b * 1024 * 1024
                       + (size_t)(h * 64) * 1024 + t0;
    const int tg = wv * 32 + l31;
#pragma unroll
    for (int cblk = 0; cblk < 2; ++cblk)
#pragma unroll
        for (int rr = 0; rr < 16; ++rr) {
            const int c = cblk * 32 + (rr & 3) + 8 * (rr >> 2) + 4 * lh;
            obase[(size_t)c * 1024 + tg] = accz[cblk][rr] * rl;
        }
}

// ---------------- Fallback (single-kernel path, ws too small) ----------------
struct S1fb {
    _Float16 K[64][72];
    _Float16 V[64][72];
    _Float16 P[128][72];
};
union SMemFb {
    S1fb s1;
    float zt[64][132];
};

__launch_bounds__(256, 4)
__global__ void qkv_attn_fallback(const float* __restrict__ qkv,
                                  float* __restrict__ out) {
    constexpr int L = 1024;
    __shared__ SMemFb sm;
    const int tid  = threadIdx.x;
    const int wv   = tid >> 6;
    const int lane = tid & 63;
    const int li   = lane & 15;
    const int quad = lane >> 4;
    const int bid  = blockIdx.x;
    const int head = (bid >> 6) * 8 + (bid & 7);
    const int tt   = (bid >> 3) & 7;
    const int b = head >> 4;
    const int h = head & 15;
    const float* qbase = qkv + (size_t)b * 3072 * L + (size_t)(h * 64) * L;
    const float* kbase = qbase + (size_t)1024 * L;
    const float* vbase = qbase + (size_t)2048 * L;
    float*       obase = out + (size_t)b * 1024 * L + (size_t)(h * 64) * L;
    const int t0 = tt * 128;
#pragma unroll
    for (int i = 0; i < 4; ++i) {
        const int c = i * 16 + (tid >> 4);
        const int t = (tid & 15) * 8;
        const float4 qa = *(const float4*)(qbase + (size_t)c * L + t0 + t);
        const float4 qb = *(const float4*)(qbase + (size_t)c * L + t0 + t + 4);
        sm.s1.P[t + 0][c] = (_Float16)(qa.x * 0.125f);
        sm.s1.P[t + 1][c] = (_Float16)(qa.y * 0.125f);
        sm.s1.P[t + 2][c] = (_Float16)(qa.z * 0.125f);
        sm.s1.P[t + 3][c] = (_Float16)(qa.w * 0.125f);
        sm.s1.P[t + 4][c] = (_Float16)(qb.x * 0.125f);
        sm.s1.P[t + 5][c] = (_Float16)(qb.y * 0.125f);
        sm.s1.P[t + 6][c] = (_Float16)(qb.z * 0.125f);
        sm.s1.P[t + 7][c] = (_Float16)(qb.w * 0.125f);
    }
    __syncthreads();
    f16x8 aq0[2], aq1[2];
#pragma unroll
    for (int kk = 0; kk < 2; ++kk) {
        aq0[kk] = *(const f16x8*)&sm.s1.P[wv * 32 + li][kk * 32 + quad * 8];
        aq1[kk] = *(const f16x8*)&sm.s1.P[wv * 32 + 16 + li][kk * 32 + quad * 8];
    }
    f32x4 accz0[4] = {}, accz1[4] = {};
    float psum0[4] = {}, psum1[4] = {};
    float4 kreg[4], vreg[4];
#pragma unroll
    for (int i = 0; i < 4; ++i) {
        const int c = i * 16 + (tid >> 4);
        const int s = (tid & 15) * 4;
        kreg[i] = *(const float4*)(kbase + (size_t)c * L + s);
        vreg[i] = *(const float4*)(vbase + (size_t)c * L + s);
    }
    for (int si = 0; si < 16; ++si) {
        __syncthreads();
#pragma unroll
        for (int i = 0; i < 4; ++i) {
            const int c = i * 16 + (tid >> 4);
            const int s = (tid & 15) * 4;
            sm.s1.K[s + 0][c] = (_Float16)kreg[i].x;
            sm.s1.K[s + 1][c] = (_Float16)kreg[i].y;
            sm.s1.K[s + 2][c] = (_Float16)kreg[i].z;
            sm.s1.K[s + 3][c] = (_Float16)kreg[i].w;
            f16x4 pv = { (_Float16)vreg[i].x, (_Float16)vreg[i].y,
                         (_Float16)vreg[i].z, (_Float16)vreg[i].w };
            *(f16x4*)&sm.s1.V[c][s] = pv;
        }
        __syncthreads();
        if (si < 15) {
            const int s0n = (si + 1) * 64;
#pragma unroll
            for (int i = 0; i < 4; ++i) {
                const int c = i * 16 + (tid >> 4);
                const int s = (tid & 15) * 4;
                kreg[i] = *(const float4*)(kbase + (size_t)c * L + s0n + s);
                vreg[i] = *(const float4*)(vbase + (size_t)c * L + s0n + s);
            }
        }
#pragma unroll
        for (int nt = 0; nt < 4; ++nt) {
            f32x4 a0 = {}, a1 = {};
#pragma unroll
            for (int kk = 0; kk < 2; ++kk) {
                f16x8 bk = *(const f16x8*)&sm.s1.K[nt * 16 + li][kk * 32 + quad * 8];
                a0 = __builtin_amdgcn_mfma_f32_16x16x32_f16(aq0[kk], bk, a0, 0, 0, 0);
                a1 = __builtin_amdgcn_mfma_f32_16x16x32_f16(aq1[kk], bk, a1, 0, 0, 0);
            }
#pragma unroll
            for (int r = 0; r < 4; ++r) {
                const float p0 = __expf(a0[r]);
                const float p1 = __expf(a1[r]);
                psum0[r] += p0;
                psum1[r] += p1;
                sm.s1.P[wv * 32 + quad * 4 + r][nt * 16 + li] = (_Float16)p0;
                sm.s1.P[wv * 32 + 16 + quad * 4 + r][nt * 16 + li] = (_Float16)p1;
            }
        }
#pragma unroll
        for (int kk = 0; kk < 2; ++kk) {
            f16x8 ap0 = *(const f16x8*)&sm.s1.P[wv * 32 + li][kk * 32 + quad * 8];
            f16x8 ap1 = *(const f16x8*)&sm.s1.P[wv * 32 + 16 + li][kk * 32 + quad * 8];
#pragma unroll
            for (int nt = 0; nt < 4; ++nt) {
                f16x8 bv = *(const f16x8*)&sm.s1.V[nt * 16 + li][kk * 32 + quad * 8];
                accz0[nt] = __builtin_amdgcn_mfma_f32_16x16x32_f16(ap0, bv, accz0[nt], 0, 0, 0);
                accz1[nt] = __builtin_amdgcn_mfma_f32_16x16x32_f16(ap1, bv, accz1[nt], 0, 0, 0);
            }
        }
    }
    float rl0[4], rl1[4];
#pragma unroll
    for (int r = 0; r < 4; ++r) {
        float s0 = psum0[r], s1 = psum1[r];
        s0 += __shfl_xor(s0, 1); s0 += __shfl_xor(s0, 2);
        s0 += __shfl_xor(s0, 4); s0 += __shfl_xor(s0, 8);
        s1 += __shfl_xor(s1, 1); s1 += __shfl_xor(s1, 2);
        s1 += __shfl_xor(s1, 4); s1 += __shfl_xor(s1, 8);
        rl0[r] = 1.0f / s0;
        rl1[r] = 1.0f / s1;
    }
    __syncthreads();
#pragma unroll
    for (int nt = 0; nt < 4; ++nt)
#pragma unroll
        for (int r = 0; r < 4; ++r) {
            sm.zt[nt * 16 + li][wv * 32 + quad * 4 + r]      = accz0[nt][r] * rl0[r];
            sm.zt[nt * 16 + li][wv * 32 + 16 + quad * 4 + r] = accz1[nt][r] * rl1[r];
        }
    __syncthreads();
#pragma unroll
    for (int i = 0; i < 8; ++i) {
        const int c = i * 8 + (tid >> 5);
        const int t = (tid & 31) * 4;
        float4 o = { sm.zt[c][t], sm.zt[c][t + 1],
                     sm.zt[c][t + 2], sm.zt[c][t + 3] };
        *(float4*)(obase + (size_t)c * L + t0 + t) = o;
    }
}

extern "C" void kernel_launch(void* const* d_in, const int* in_sizes, int n_in,
                              void* d_out, int out_size, void* d_ws, size_t ws_size,
                              hipStream_t stream) {
    const float* qkv = (const float*)d_in[0];
    float* out = (float*)d_out;
    if (ws_size >= (size_t)WS_BYTES) {
        _Float16* ws = (_Float16*)d_ws;
        prepass_kv<<<4096, 256, 0, stream>>>(qkv, ws);
        // 128 heads x 4 t-tiles of 256; 512-thread blocks -> 2 blocks/CU
        attn_kernel<<<512, 512, 0, stream>>>(qkv, ws, out);
    } else {
        qkv_attn_fallback<<<1024, 256, 0, stream>>>(qkv, out);
    }
}